// Round 1
// baseline (42226.456 us; speedup 1.0000x reference)
//
#include <hip/hip_runtime.h>
#include <hip/hip_bf16.h>

#define T_STEPS 256
#define BATCH   128
#define IDIM    512
#define HDIM    1024
#define NLAYERS 4
#define G3      (3 * HDIM)
#define BH      (BATCH * HDIM)   // 131072 elements
#define CHUNK   16               // timesteps per gi precompute chunk
#define CROWS   (CHUNK * BATCH)  // 2048 rows per chunk GEMM
#define NBLK    256              // persistent kernel: 1 block per CU

typedef __bf16 bf16_t;
typedef __bf16 bf16x4 __attribute__((ext_vector_type(4)));
typedef __bf16 bf16x8 __attribute__((ext_vector_type(8)));
typedef float  f32x4  __attribute__((ext_vector_type(4)));

__device__ __forceinline__ float sigm_f(float x) { return 1.0f / (1.0f + __expf(-x)); }
__device__ __forceinline__ float tanh_f(float x) { return 1.0f - 2.0f / (__expf(2.0f * x) + 1.0f); }

__device__ __forceinline__ bf16x8 cvt8(const float* p) {
    f32x4 v0 = *(const f32x4*)p;
    f32x4 v1 = *(const f32x4*)(p + 4);
    bf16x8 o;
    o[0] = (bf16_t)v0[0]; o[1] = (bf16_t)v0[1]; o[2] = (bf16_t)v0[2]; o[3] = (bf16_t)v0[3];
    o[4] = (bf16_t)v1[0]; o[5] = (bf16_t)v1[1]; o[6] = (bf16_t)v1[2]; o[7] = (bf16_t)v1[3];
    return o;
}

// fp32 -> bf16, 4 elements per thread. n4 = n/4.
__global__ void cvt_f2b(const float* __restrict__ s, bf16_t* __restrict__ d, int n4) {
    int i = blockIdx.x * blockDim.x + threadIdx.x;
    if (i < n4) {
        f32x4 v = ((const f32x4*)s)[i];
        bf16x4 o;
        o[0] = (bf16_t)v[0]; o[1] = (bf16_t)v[1];
        o[2] = (bf16_t)v[2]; o[3] = (bf16_t)v[3];
        ((bf16x4*)d)[i] = o;
    }
}

// fp32 h -> bf16 hi/lo split + fp32 carry copy, 4 per thread over BH elements.
__global__ void split_h3(const float* __restrict__ s,
                         bf16_t* __restrict__ hi, bf16_t* __restrict__ lo,
                         float* __restrict__ carry) {
    int i = blockIdx.x * blockDim.x + threadIdx.x;  // < BH/4
    f32x4 v = ((const f32x4*)s)[i];
    bf16x4 h, l;
#pragma unroll
    for (int j = 0; j < 4; ++j) {
        bf16_t t = (bf16_t)v[j];
        h[j] = t;
        l[j] = (bf16_t)(v[j] - (float)t);
    }
    ((bf16x4*)hi)[i] = h;
    ((bf16x4*)lo)[i] = l;
    ((f32x4*)carry)[i] = v;
}

__global__ void init_bar(unsigned* b) { b[0] = 0u; b[1] = 0u; }

// Phase A: gi[chunk] = ys_rows @ W_ih^T + b_ih.  (unchanged from previous version)
template <int HIN>
__global__ __launch_bounds__(64)
void gi_gemm(const float*  __restrict__ ysrc,
             const bf16_t* __restrict__ w_ih,
             const float*  __restrict__ b_ih,
             float* __restrict__ gi,
             int row0)
{
    const int lane = threadIdx.x;
    const int cq   = lane & 15;
    const int quad = lane >> 4;
    const int n0   = blockIdx.x * 64;
    const int m0   = blockIdx.y * 32;

    const float* a0p = ysrc + (size_t)(row0 + m0 + cq) * HIN + quad * 8;
    const float* a1p = a0p + (size_t)16 * HIN;
    const bf16_t* b0p = w_ih + (size_t)(n0 + cq) * HIN + quad * 8;
    const bf16_t* b1p = b0p + (size_t)16 * HIN;
    const bf16_t* b2p = b0p + (size_t)32 * HIN;
    const bf16_t* b3p = b0p + (size_t)48 * HIN;

    f32x4 a00{0,0,0,0}, a01 = a00, a02 = a00, a03 = a00;
    f32x4 a10 = a00, a11 = a00, a12 = a00, a13 = a00;

#pragma unroll 4
    for (int k = 0; k < HIN; k += 32) {
        bf16x8 fa0 = cvt8(a0p + k);
        bf16x8 fa1 = cvt8(a1p + k);
        bf16x8 fb0 = *(const bf16x8*)(b0p + k);
        bf16x8 fb1 = *(const bf16x8*)(b1p + k);
        bf16x8 fb2 = *(const bf16x8*)(b2p + k);
        bf16x8 fb3 = *(const bf16x8*)(b3p + k);
        a00 = __builtin_amdgcn_mfma_f32_16x16x32_bf16(fa0, fb0, a00, 0, 0, 0);
        a01 = __builtin_amdgcn_mfma_f32_16x16x32_bf16(fa0, fb1, a01, 0, 0, 0);
        a02 = __builtin_amdgcn_mfma_f32_16x16x32_bf16(fa0, fb2, a02, 0, 0, 0);
        a03 = __builtin_amdgcn_mfma_f32_16x16x32_bf16(fa0, fb3, a03, 0, 0, 0);
        a10 = __builtin_amdgcn_mfma_f32_16x16x32_bf16(fa1, fb0, a10, 0, 0, 0);
        a11 = __builtin_amdgcn_mfma_f32_16x16x32_bf16(fa1, fb1, a11, 0, 0, 0);
        a12 = __builtin_amdgcn_mfma_f32_16x16x32_bf16(fa1, fb2, a12, 0, 0, 0);
        a13 = __builtin_amdgcn_mfma_f32_16x16x32_bf16(fa1, fb3, a13, 0, 0, 0);
    }

    const float bb0 = b_ih[n0 + 0  + cq];
    const float bb1 = b_ih[n0 + 16 + cq];
    const float bb2 = b_ih[n0 + 32 + cq];
    const float bb3 = b_ih[n0 + 48 + cq];

#pragma unroll
    for (int i = 0; i < 4; ++i) {
        const int r0 = m0 + quad * 4 + i;
        const int r1 = r0 + 16;
        float* g0 = gi + (size_t)r0 * G3 + n0 + cq;
        float* g1 = gi + (size_t)r1 * G3 + n0 + cq;
        g0[0]  = a00[i] + bb0;  g0[16] = a01[i] + bb1;
        g0[32] = a02[i] + bb2;  g0[48] = a03[i] + bb3;
        g1[0]  = a10[i] + bb0;  g1[16] = a11[i] + bb1;
        g1[32] = a12[i] + bb2;  g1[48] = a13[i] + bb3;
    }
}

// Device-wide sense-reversing barrier. Safe across non-coherent XCD L2s:
// release side flushes local L2 (agent fence), arrival/release via agent-scope
// atomics, acquire side invalidates before re-reading h buffers.
// Requires all NBLK blocks co-resident (1 block/CU: 144KB LDS, grid=256).
__device__ __forceinline__ void grid_sync(unsigned* bar) {
    __syncthreads();
    if (threadIdx.x == 0) {
        __threadfence();  // agent-scope release: flush this XCD's L2
        unsigned ph  = __hip_atomic_load(bar + 1, __ATOMIC_RELAXED, __HIP_MEMORY_SCOPE_AGENT);
        unsigned old = __hip_atomic_fetch_add(bar, 1u, __ATOMIC_ACQ_REL, __HIP_MEMORY_SCOPE_AGENT);
        if (old == NBLK - 1u) {
            __hip_atomic_store(bar, 0u, __ATOMIC_RELAXED, __HIP_MEMORY_SCOPE_AGENT);
            __hip_atomic_store(bar + 1, ph + 1u, __ATOMIC_RELEASE, __HIP_MEMORY_SCOPE_AGENT);
        } else {
            while (__hip_atomic_load(bar + 1, __ATOMIC_ACQUIRE, __HIP_MEMORY_SCOPE_AGENT) == ph) {
                __builtin_amdgcn_s_sleep(1);
            }
        }
        __threadfence();  // agent-scope acquire: invalidate stale L1/L2 lines
    }
    __syncthreads();
}

// Phase B (persistent): all 16 timesteps of a chunk in ONE launch.
// Grid 256 blocks = (64 col-groups x 4 batch-groups), 512 threads (8 waves).
// Block owns cols [cg*16,+16) of all 3 gates and batch rows [bg*32,+32).
// W_hh tile staged once into LDS in MFMA-fragment order (96 KB).
// Wave w = K-eighth [w*128,+128); computes all 32 rows x 3 gates (6 f32x4 acc).
// LDS reduction over 8 partials; waves 0-1 do gate math, holding h as exact
// fp32 in registers across steps; bf16 hi/lo published each step for other
// blocks' A-operands. Custom device barrier between steps.
__global__ __launch_bounds__(512, 2)
void gru_chunk(const float*  __restrict__ gi,     // (CROWS, 3H) fp32
               const bf16_t* __restrict__ w_hh,   // (3H, H) bf16
               const float*  __restrict__ b_hh,   // (3H) fp32
               bf16_t* hhi0, bf16_t* hlo0,
               bf16_t* hhi1, bf16_t* hlo1,
               float* __restrict__ h_carry,       // (B, H) fp32 in/out
               float* __restrict__ ys,            // (T, B, H) fp32 out base
               const int* __restrict__ lengths,
               int t0,
               float* __restrict__ hfin_l,        // (B, H) fp32 for this layer
               unsigned* bar)
{
    __shared__ bf16x8 wfrag[3 * 32 * 64];     // 96 KB, fragment-ordered
    __shared__ f32x4  red[8][3][2][64];       // 48 KB  [kq][gate][mh][lane]

    const int tid  = threadIdx.x;
    const int wid  = tid >> 6;          // wave id = K-eighth
    const int lane = tid & 63;
    const int cq   = lane & 15;
    const int quad = lane >> 4;
    const int cg   = blockIdx.x;        // 0..63
    const int bg   = blockIdx.y;        // 0..3
    const int c0   = cg * 16;
    const int col  = c0 + cq;

    // Stage W_hh fragments: frag (g, kc, ln) holds w_hh[col=c0+(ln&15)][kc*32+(ln>>4)*8 ..+8]
    for (int f = tid; f < 3 * 32 * 64; f += 512) {
        const int g  = f >> 11;
        const int kc = (f >> 6) & 31;
        const int ln = f & 63;
        wfrag[f] = *(const bf16x8*)(w_hh
            + (size_t)(g * HDIM + c0 + (ln & 15)) * HDIM + kc * 32 + (ln >> 4) * 8);
    }

    // Gate-owner state (waves 0-1 only): exact fp32 h, lengths, b_hh.
    float hold[4];
    int   len[4];
    float bhr = 0.f, bhz = 0.f, bhn = 0.f;
    if (tid < 128) {
        bhr = b_hh[col]; bhz = b_hh[HDIM + col]; bhn = b_hh[2 * HDIM + col];
#pragma unroll
        for (int i = 0; i < 4; ++i) {
            const int row = bg * 32 + wid * 16 + quad * 4 + i;
            hold[i] = h_carry[(size_t)row * HDIM + col];
            len[i]  = lengths[row];
        }
    }
    __syncthreads();

    // A-operand element offsets for this wave (mh=0 / mh=1 row halves).
    const size_t arow0 = (size_t)(bg * 32 + cq) * HDIM + wid * 128 + quad * 8;
    const size_t arow1 = arow0 + (size_t)16 * HDIM;

#pragma unroll 1
    for (int tt = 0; tt < CHUNK; ++tt) {
        const int t = t0 + tt;
        const bool rd0 = ((t & 1) == 0);
        const bf16_t* phi = rd0 ? hhi0 : hhi1;
        const bf16_t* plo = rd0 ? hlo0 : hlo1;
        bf16_t* ohi = rd0 ? hhi1 : hhi0;
        bf16_t* olo = rd0 ? hlo1 : hlo0;

        f32x4 a00{0,0,0,0}, a10 = a00, a20 = a00, a01 = a00, a11 = a00, a21 = a00;

#pragma unroll
        for (int j = 0; j < 4; ++j) {
            const bf16x8 B0 = wfrag[(0 * 32 + wid * 4 + j) * 64 + lane];
            const bf16x8 B1 = wfrag[(1 * 32 + wid * 4 + j) * 64 + lane];
            const bf16x8 B2 = wfrag[(2 * 32 + wid * 4 + j) * 64 + lane];
            const bf16x8 Ah0 = *(const bf16x8*)(phi + arow0 + j * 32);
            const bf16x8 Ah1 = *(const bf16x8*)(phi + arow1 + j * 32);
            const bf16x8 Al0 = *(const bf16x8*)(plo + arow0 + j * 32);
            const bf16x8 Al1 = *(const bf16x8*)(plo + arow1 + j * 32);
            a00 = __builtin_amdgcn_mfma_f32_16x16x32_bf16(Ah0, B0, a00, 0, 0, 0);
            a10 = __builtin_amdgcn_mfma_f32_16x16x32_bf16(Ah0, B1, a10, 0, 0, 0);
            a20 = __builtin_amdgcn_mfma_f32_16x16x32_bf16(Ah0, B2, a20, 0, 0, 0);
            a01 = __builtin_amdgcn_mfma_f32_16x16x32_bf16(Ah1, B0, a01, 0, 0, 0);
            a11 = __builtin_amdgcn_mfma_f32_16x16x32_bf16(Ah1, B1, a11, 0, 0, 0);
            a21 = __builtin_amdgcn_mfma_f32_16x16x32_bf16(Ah1, B2, a21, 0, 0, 0);
            a00 = __builtin_amdgcn_mfma_f32_16x16x32_bf16(Al0, B0, a00, 0, 0, 0);
            a10 = __builtin_amdgcn_mfma_f32_16x16x32_bf16(Al0, B1, a10, 0, 0, 0);
            a20 = __builtin_amdgcn_mfma_f32_16x16x32_bf16(Al0, B2, a20, 0, 0, 0);
            a01 = __builtin_amdgcn_mfma_f32_16x16x32_bf16(Al1, B0, a01, 0, 0, 0);
            a11 = __builtin_amdgcn_mfma_f32_16x16x32_bf16(Al1, B1, a11, 0, 0, 0);
            a21 = __builtin_amdgcn_mfma_f32_16x16x32_bf16(Al1, B2, a21, 0, 0, 0);
        }

        red[wid][0][0][lane] = a00; red[wid][0][1][lane] = a01;
        red[wid][1][0][lane] = a10; red[wid][1][1][lane] = a11;
        red[wid][2][0][lane] = a20; red[wid][2][1][lane] = a21;
        __syncthreads();

        if (tid < 128) {
            const int mh = wid;   // 0 or 1
            f32x4 sr = red[0][0][mh][lane];
            f32x4 sz = red[0][1][mh][lane];
            f32x4 sn = red[0][2][mh][lane];
#pragma unroll
            for (int q = 1; q < 8; ++q) {
                sr += red[q][0][mh][lane];
                sz += red[q][1][mh][lane];
                sn += red[q][2][mh][lane];
            }
            const float* gbase = gi + (size_t)(tt * BATCH) * G3 + col;
#pragma unroll
            for (int i = 0; i < 4; ++i) {
                const int row = bg * 32 + mh * 16 + quad * 4 + i;
                const float* gr = gbase + (size_t)row * G3;
                const float ir  = gr[0];
                const float iz  = gr[HDIM];
                const float inn = gr[2 * HDIM];
                const float r = sigm_f(ir + sr[i] + bhr);
                const float z = sigm_f(iz + sz[i] + bhz);
                const float n = tanh_f(inn + r * (sn[i] + bhn));
                const float hnew = (1.0f - z) * n + z * hold[i];
                const bool  msk = t < len[i];
                const float hnext = msk ? hnew : hold[i];
                hold[i] = hnext;
                const size_t oh = (size_t)row * HDIM + col;
                const bf16_t hb = (bf16_t)hnext;
                ohi[oh] = hb;
                olo[oh] = (bf16_t)(hnext - (float)hb);
                ys[(size_t)t * BH + oh] = msk ? hnew : 0.0f;
                if (t == T_STEPS - 1) hfin_l[oh] = hnext;
            }
        }
        if (tt != CHUNK - 1) grid_sync(bar);
    }

    // Persist exact fp32 h for the next chunk launch.
    if (tid < 128) {
#pragma unroll
        for (int i = 0; i < 4; ++i) {
            const int row = bg * 32 + wid * 16 + quad * 4 + i;
            h_carry[(size_t)row * HDIM + col] = hold[i];
        }
    }
}

extern "C" void kernel_launch(void* const* d_in, const int* in_sizes, int n_in,
                              void* d_out, int out_size, void* d_ws, size_t ws_size,
                              hipStream_t stream) {
    const float* x         = (const float*)d_in[0];
    const float* hidden    = (const float*)d_in[1];
    const float* w_ih0     = (const float*)d_in[2];
    const float* w_ih_rest = (const float*)d_in[3];
    const float* w_hh      = (const float*)d_in[4];
    const float* b_ih      = (const float*)d_in[5];
    const float* b_hh      = (const float*)d_in[6];
    const int*   lengths   = (const int*)d_in[8];

    float* ys   = (float*)d_out;               // (T, B, H) fp32
    float* hfin = ys + (size_t)T_STEPS * BH;   // (L, B, H) fp32

    // Workspace (~74.5 MB): bf16 weights (47.2), h hi/lo (1), fp32 carry (0.5),
    // gi chunk (25.2), barrier (8 B).
    char* ws = (char*)d_ws;
    bf16_t* wb_ih0  = (bf16_t*)ws;                                   // 3072*512
    bf16_t* wb_rest = wb_ih0 + (size_t)G3 * IDIM;                    // 3*3072*1024
    bf16_t* wb_hh   = wb_rest + (size_t)(NLAYERS - 1) * G3 * HDIM;   // 4*3072*1024
    bf16_t* hhi0 = wb_hh + (size_t)NLAYERS * G3 * HDIM;
    bf16_t* hlo0 = hhi0 + BH;
    bf16_t* hhi1 = hlo0 + BH;
    bf16_t* hlo1 = hhi1 + BH;
    float*  h_carry = (float*)(hlo1 + BH);
    float*  gi   = h_carry + BH;               // (CROWS, 3H) fp32 chunk buffer
    unsigned* bar = (unsigned*)(gi + (size_t)CROWS * G3);

    init_bar<<<1, 1, 0, stream>>>(bar);

    // Convert all weights fp32 -> bf16 once.
    {
        int n4;
        n4 = G3 * IDIM / 4;
        cvt_f2b<<<(n4 + 255) / 256, 256, 0, stream>>>(w_ih0, wb_ih0, n4);
        n4 = (NLAYERS - 1) * G3 * HDIM / 4;
        cvt_f2b<<<(n4 + 255) / 256, 256, 0, stream>>>(w_ih_rest, wb_rest, n4);
        n4 = NLAYERS * G3 * HDIM / 4;
        cvt_f2b<<<(n4 + 255) / 256, 256, 0, stream>>>(w_hh, wb_hh, n4);
    }

    dim3 gridA(G3 / 64, CROWS / 32);   // (48, 64)
    dim3 gridB(64, 4);                 // persistent: 256 blocks = 1/CU

    for (int l = 0; l < NLAYERS; ++l) {
        const bf16_t* wb_ih_l = (l == 0) ? wb_ih0 : (wb_rest + (size_t)(l - 1) * G3 * HDIM);
        const bf16_t* wb_hh_l = wb_hh + (size_t)l * G3 * HDIM;
        const float*  b_ih_l  = b_ih + (size_t)l * G3;
        const float*  b_hh_l  = b_hh + (size_t)l * G3;

        // Seed hi/lo slot 0 and the fp32 carry with this layer's initial hidden.
        split_h3<<<BH / 4 / 256, 256, 0, stream>>>(hidden + (size_t)l * BH, hhi0, hlo0, h_carry);

        for (int c = 0; c < T_STEPS / CHUNK; ++c) {
            const int t0 = c * CHUNK;
            // Phase A: gi for this chunk (reads layer input before the in-place
            // step kernel overwrites those ys slices).
            if (l == 0) {
                gi_gemm<IDIM><<<gridA, 64, 0, stream>>>(x, wb_ih_l, b_ih_l, gi, t0 * BATCH);
            } else {
                gi_gemm<HDIM><<<gridA, 64, 0, stream>>>(ys, wb_ih_l, b_ih_l, gi, t0 * BATCH);
            }
            // Phase B: all 16 steps in one persistent launch.
            gru_chunk<<<gridB, 512, 0, stream>>>(
                gi, wb_hh_l, b_hh_l,
                hhi0, hlo0, hhi1, hlo1,
                h_carry, ys, lengths, t0,
                hfin + (size_t)l * BH, bar);
        }
    }
}

// Round 2
// 15743.597 us; speedup vs baseline: 2.6821x; 2.6821x over previous
//
#include <hip/hip_runtime.h>
#include <hip/hip_bf16.h>

#define T_STEPS 256
#define BATCH   128
#define IDIM    512
#define HDIM    1024
#define NLAYERS 4
#define G3      (3 * HDIM)
#define BH      (BATCH * HDIM)   // 131072 elements

typedef __bf16 bf16_t;
typedef __bf16 bf16x4 __attribute__((ext_vector_type(4)));
typedef __bf16 bf16x8 __attribute__((ext_vector_type(8)));
typedef float  f32x4  __attribute__((ext_vector_type(4)));

__device__ __forceinline__ float sigm_f(float x) { return 1.0f / (1.0f + __expf(-x)); }
__device__ __forceinline__ float tanh_f(float x) { return 1.0f - 2.0f / (__expf(2.0f * x) + 1.0f); }

__device__ __forceinline__ bf16x8 cvt8(const float* p) {
    f32x4 v0 = *(const f32x4*)p;
    f32x4 v1 = *(const f32x4*)(p + 4);
    bf16x8 o;
    o[0] = (bf16_t)v0[0]; o[1] = (bf16_t)v0[1]; o[2] = (bf16_t)v0[2]; o[3] = (bf16_t)v0[3];
    o[4] = (bf16_t)v1[0]; o[5] = (bf16_t)v1[1]; o[6] = (bf16_t)v1[2]; o[7] = (bf16_t)v1[3];
    return o;
}

// fp32 -> bf16, 4 elements per thread. n4 = n/4.
__global__ void cvt_f2b(const float* __restrict__ s, bf16_t* __restrict__ d, int n4) {
    int i = blockIdx.x * blockDim.x + threadIdx.x;
    if (i < n4) {
        f32x4 v = ((const f32x4*)s)[i];
        bf16x4 o;
        o[0] = (bf16_t)v[0]; o[1] = (bf16_t)v[1];
        o[2] = (bf16_t)v[2]; o[3] = (bf16_t)v[3];
        ((bf16x4*)d)[i] = o;
    }
}

// fp32 h -> bf16 hi/lo split, 4 per thread over BH elements.
__global__ void split_h(const float* __restrict__ s,
                        bf16_t* __restrict__ hi, bf16_t* __restrict__ lo) {
    int i = blockIdx.x * blockDim.x + threadIdx.x;  // < BH/4
    f32x4 v = ((const f32x4*)s)[i];
    bf16x4 h, l;
#pragma unroll
    for (int j = 0; j < 4; ++j) {
        bf16_t t = (bf16_t)v[j];
        h[j] = t;
        l[j] = (bf16_t)(v[j] - (float)t);
    }
    ((bf16x4*)hi)[i] = h;
    ((bf16x4*)lo)[i] = l;
}

// Phase A: gi[chunk] = ys_rows @ W_ih^T + b_ih.  fp32 in (converted in-register),
// bf16 weights, fp32 out. One wave per WG; wave computes a 32x64 C-tile.
template <int HIN>
__global__ __launch_bounds__(64)
void gi_gemm(const float*  __restrict__ ysrc,
             const bf16_t* __restrict__ w_ih,
             const float*  __restrict__ b_ih,
             float* __restrict__ gi,
             int row0)
{
    const int lane = threadIdx.x;
    const int cq   = lane & 15;
    const int quad = lane >> 4;
    const int n0   = blockIdx.x * 64;
    const int m0   = blockIdx.y * 32;

    const float* a0p = ysrc + (size_t)(row0 + m0 + cq) * HIN + quad * 8;
    const float* a1p = a0p + (size_t)16 * HIN;
    const bf16_t* b0p = w_ih + (size_t)(n0 + cq) * HIN + quad * 8;
    const bf16_t* b1p = b0p + (size_t)16 * HIN;
    const bf16_t* b2p = b0p + (size_t)32 * HIN;
    const bf16_t* b3p = b0p + (size_t)48 * HIN;

    f32x4 a00{0,0,0,0}, a01 = a00, a02 = a00, a03 = a00;
    f32x4 a10 = a00, a11 = a00, a12 = a00, a13 = a00;

#pragma unroll 4
    for (int k = 0; k < HIN; k += 32) {
        bf16x8 fa0 = cvt8(a0p + k);
        bf16x8 fa1 = cvt8(a1p + k);
        bf16x8 fb0 = *(const bf16x8*)(b0p + k);
        bf16x8 fb1 = *(const bf16x8*)(b1p + k);
        bf16x8 fb2 = *(const bf16x8*)(b2p + k);
        bf16x8 fb3 = *(const bf16x8*)(b3p + k);
        a00 = __builtin_amdgcn_mfma_f32_16x16x32_bf16(fa0, fb0, a00, 0, 0, 0);
        a01 = __builtin_amdgcn_mfma_f32_16x16x32_bf16(fa0, fb1, a01, 0, 0, 0);
        a02 = __builtin_amdgcn_mfma_f32_16x16x32_bf16(fa0, fb2, a02, 0, 0, 0);
        a03 = __builtin_amdgcn_mfma_f32_16x16x32_bf16(fa0, fb3, a03, 0, 0, 0);
        a10 = __builtin_amdgcn_mfma_f32_16x16x32_bf16(fa1, fb0, a10, 0, 0, 0);
        a11 = __builtin_amdgcn_mfma_f32_16x16x32_bf16(fa1, fb1, a11, 0, 0, 0);
        a12 = __builtin_amdgcn_mfma_f32_16x16x32_bf16(fa1, fb2, a12, 0, 0, 0);
        a13 = __builtin_amdgcn_mfma_f32_16x16x32_bf16(fa1, fb3, a13, 0, 0, 0);
    }

    const float bb0 = b_ih[n0 + 0  + cq];
    const float bb1 = b_ih[n0 + 16 + cq];
    const float bb2 = b_ih[n0 + 32 + cq];
    const float bb3 = b_ih[n0 + 48 + cq];

#pragma unroll
    for (int i = 0; i < 4; ++i) {
        const int r0 = m0 + quad * 4 + i;
        const int r1 = r0 + 16;
        float* g0 = gi + (size_t)r0 * G3 + n0 + cq;
        float* g1 = gi + (size_t)r1 * G3 + n0 + cq;
        g0[0]  = a00[i] + bb0;  g0[16] = a01[i] + bb1;
        g0[32] = a02[i] + bb2;  g0[48] = a03[i] + bb3;
        g1[0]  = a10[i] + bb0;  g1[16] = a11[i] + bb1;
        g1[32] = a12[i] + bb2;  g1[48] = a13[i] + bb3;
    }
}

// Per-active-layer parameters for one fused timestep.
struct LayerStep {
    const float*  gi_t;      // (B, 3H) fp32, this timestep (includes b_ih)
    const bf16_t* w_hh;      // (3H, H) bf16
    const float*  b_hh;      // (3H) fp32
    const bf16_t* h_in_hi;
    const bf16_t* h_in_lo;
    bf16_t*       h_out_hi;
    bf16_t*       h_out_lo;
    float*        y_t;       // (B, H) fp32 output slice
    float*        h_final;   // (B, H) fp32 or nullptr
    int           t;
};
struct StepArgs { LayerStep L[NLAYERS]; };

// Phase B: one GRU timestep for up to 4 independent (layer, chunk) pairs
// (wavefront pipelining). Grid (64 col-tiles, 8 batch-tiles, n_active) x 256
// threads (4 waves = K-quarters). Body identical to the verified gru_step2.
__global__ __launch_bounds__(256)
void gru_step_multi(StepArgs args, const int* __restrict__ lengths)
{
    __shared__ f32x4 red[4][3][64];   // [k-quarter][gate][lane]

    const LayerStep& A = args.L[blockIdx.z];

    const int tid  = threadIdx.x;
    const int s    = tid >> 6;        // K-quarter 0..3
    const int lane = tid & 63;
    const int cq   = lane & 15;
    const int quad = lane >> 4;
    const int c0   = blockIdx.x * 16; // hidden col tile
    const int m0   = blockIdx.y * 16; // batch tile

    const bf16_t* ap_hi = A.h_in_hi + (size_t)(m0 + cq) * HDIM + s * 256 + quad * 8;
    const bf16_t* ap_lo = A.h_in_lo + (size_t)(m0 + cq) * HDIM + s * 256 + quad * 8;
    const bf16_t* bp0 = A.w_hh + (size_t)(0 * HDIM + c0 + cq) * HDIM + s * 256 + quad * 8;
    const bf16_t* bp1 = A.w_hh + (size_t)(1 * HDIM + c0 + cq) * HDIM + s * 256 + quad * 8;
    const bf16_t* bp2 = A.w_hh + (size_t)(2 * HDIM + c0 + cq) * HDIM + s * 256 + quad * 8;

    f32x4 ac0{0,0,0,0}, ac1 = ac0, ac2 = ac0;

#pragma unroll
    for (int k = 0; k < 256; k += 32) {
        bf16x8 ahi = *(const bf16x8*)(ap_hi + k);
        bf16x8 alo = *(const bf16x8*)(ap_lo + k);
        bf16x8 b0  = *(const bf16x8*)(bp0 + k);
        bf16x8 b1  = *(const bf16x8*)(bp1 + k);
        bf16x8 b2  = *(const bf16x8*)(bp2 + k);
        ac0 = __builtin_amdgcn_mfma_f32_16x16x32_bf16(ahi, b0, ac0, 0, 0, 0);
        ac1 = __builtin_amdgcn_mfma_f32_16x16x32_bf16(ahi, b1, ac1, 0, 0, 0);
        ac2 = __builtin_amdgcn_mfma_f32_16x16x32_bf16(ahi, b2, ac2, 0, 0, 0);
        ac0 = __builtin_amdgcn_mfma_f32_16x16x32_bf16(alo, b0, ac0, 0, 0, 0);
        ac1 = __builtin_amdgcn_mfma_f32_16x16x32_bf16(alo, b1, ac1, 0, 0, 0);
        ac2 = __builtin_amdgcn_mfma_f32_16x16x32_bf16(alo, b2, ac2, 0, 0, 0);
    }
    red[s][0][lane] = ac0;
    red[s][1][lane] = ac1;
    red[s][2][lane] = ac2;
    __syncthreads();

    if (s == 0) {
        const int col = c0 + cq;
        const float bhr = A.b_hh[col];
        const float bhz = A.b_hh[HDIM + col];
        const float bhn = A.b_hh[2 * HDIM + col];
#pragma unroll
        for (int i = 0; i < 4; ++i) {
            const int row = m0 + quad * 4 + i;   // batch index
            const size_t oh = (size_t)row * HDIM + col;
            const float hr = red[0][0][lane][i] + red[1][0][lane][i]
                           + red[2][0][lane][i] + red[3][0][lane][i];
            const float hz = red[0][1][lane][i] + red[1][1][lane][i]
                           + red[2][1][lane][i] + red[3][1][lane][i];
            const float hn = red[0][2][lane][i] + red[1][2][lane][i]
                           + red[2][2][lane][i] + red[3][2][lane][i];
            const float* gr = A.gi_t + (size_t)row * G3;
            const float ir  = gr[col];
            const float iz  = gr[HDIM + col];
            const float inn = gr[2 * HDIM + col];
            const float hold = (float)A.h_in_hi[oh] + (float)A.h_in_lo[oh];
            const float r = sigm_f(ir + hr + bhr);
            const float z = sigm_f(iz + hz + bhz);
            const float n = tanh_f(inn + r * (hn + bhn));
            const float hnew = (1.0f - z) * n + z * hold;
            const bool msk = A.t < lengths[row];
            const float hnext = msk ? hnew : hold;
            const bf16_t hb = (bf16_t)hnext;
            A.h_out_hi[oh] = hb;
            A.h_out_lo[oh] = (bf16_t)(hnext - (float)hb);
            A.y_t[oh] = msk ? hnew : 0.0f;
            if (A.h_final) A.h_final[oh] = hnext;
        }
    }
}

extern "C" void kernel_launch(void* const* d_in, const int* in_sizes, int n_in,
                              void* d_out, int out_size, void* d_ws, size_t ws_size,
                              hipStream_t stream) {
    const float* x         = (const float*)d_in[0];
    const float* hidden    = (const float*)d_in[1];
    const float* w_ih0     = (const float*)d_in[2];
    const float* w_ih_rest = (const float*)d_in[3];
    const float* w_hh      = (const float*)d_in[4];
    const float* b_ih      = (const float*)d_in[5];
    const float* b_hh      = (const float*)d_in[6];
    const int*   lengths   = (const int*)d_in[8];

    float* ys   = (float*)d_out;               // (T, B, H) fp32
    float* hfin = ys + (size_t)T_STEPS * BH;   // (L, B, H) fp32

    // Workspace layout: bf16 weights (47.2 MB), per-layer h hi/lo ping-pong
    // (4 x 1 MB), per-layer gi chunk buffers (4 x chunk x 128 x 3072 x 4 B).
    char* ws = (char*)d_ws;
    bf16_t* wb_ih0  = (bf16_t*)ws;                                   // 3072*512
    bf16_t* wb_rest = wb_ih0 + (size_t)G3 * IDIM;                    // 3*3072*1024
    bf16_t* wb_hh   = wb_rest + (size_t)(NLAYERS - 1) * G3 * HDIM;   // 4*3072*1024
    bf16_t* hbase   = wb_hh + (size_t)NLAYERS * G3 * HDIM;           // 4 layers * 4*BH
    float*  gi_base = (float*)(hbase + (size_t)NLAYERS * 4 * BH);

    const size_t fixed_bytes = (size_t)((char*)gi_base - ws);
    // Runtime chunk size: largest of {16,8,4,2} whose gi buffers fit ws.
    int chunk = 16;
    while (chunk > 2 &&
           fixed_bytes + (size_t)NLAYERS * chunk * BATCH * G3 * sizeof(float) > ws_size)
        chunk >>= 1;
    const int nch = T_STEPS / chunk;
    const size_t gi_stride = (size_t)chunk * BATCH * G3;  // floats per layer buffer

    // Convert all weights fp32 -> bf16 once.
    {
        int n4;
        n4 = G3 * IDIM / 4;
        cvt_f2b<<<(n4 + 255) / 256, 256, 0, stream>>>(w_ih0, wb_ih0, n4);
        n4 = (NLAYERS - 1) * G3 * HDIM / 4;
        cvt_f2b<<<(n4 + 255) / 256, 256, 0, stream>>>(w_ih_rest, wb_rest, n4);
        n4 = NLAYERS * G3 * HDIM / 4;
        cvt_f2b<<<(n4 + 255) / 256, 256, 0, stream>>>(w_hh, wb_hh, n4);
    }

    // Seed every layer's h ping-pong slot 0 with its initial hidden state.
    for (int l = 0; l < NLAYERS; ++l) {
        bf16_t* hb = hbase + (size_t)l * 4 * BH;
        split_h<<<BH / 4 / 256, 256, 0, stream>>>(hidden + (size_t)l * BH, hb, hb + BH);
    }

    const dim3 gridA(G3 / 64, chunk * BATCH / 32);

    // Wavefront over chunks: iteration s runs (layer l, chunk c=s-l) for all
    // valid l concurrently. Layer l's Phase A at iteration s reads ys chunk c
    // (written by layer l-1 at iteration s-1) before layer l's own steps
    // overwrite that ys slice later in this iteration (stream order).
    for (int s = 0; s < nch + NLAYERS - 1; ++s) {
        // Phase A for each newly-active (layer, chunk).
        for (int l = 0; l < NLAYERS; ++l) {
            const int c = s - l;
            if (c < 0 || c >= nch) continue;
            float* gi_l = gi_base + (size_t)l * gi_stride;
            const bf16_t* wb_ih_l = (l == 0) ? wb_ih0 : (wb_rest + (size_t)(l - 1) * G3 * HDIM);
            const float*  b_ih_l  = b_ih + (size_t)l * G3;
            const int row0 = c * chunk * BATCH;
            if (l == 0) {
                gi_gemm<IDIM><<<gridA, 64, 0, stream>>>(x, wb_ih_l, b_ih_l, gi_l, row0);
            } else {
                gi_gemm<HDIM><<<gridA, 64, 0, stream>>>(ys, wb_ih_l, b_ih_l, gi_l, row0);
            }
        }
        // Fused steps: all active layers advance together.
        for (int tt = 0; tt < chunk; ++tt) {
            StepArgs sa;
            int na = 0;
            for (int l = 0; l < NLAYERS; ++l) {
                const int c = s - l;
                if (c < 0 || c >= nch) continue;
                const int t = c * chunk + tt;
                // chunk is even => parity(t) == parity(tt), but use t directly.
                const bool rd0 = ((t & 1) == 0);
                bf16_t* hb = hbase + (size_t)l * 4 * BH;
                bf16_t* hhi0 = hb, *hlo0 = hb + BH, *hhi1 = hb + 2 * BH, *hlo1 = hb + 3 * BH;
                LayerStep& P = sa.L[na++];
                P.gi_t     = gi_base + (size_t)l * gi_stride + (size_t)tt * BATCH * G3;
                P.w_hh     = wb_hh + (size_t)l * G3 * HDIM;
                P.b_hh     = b_hh + (size_t)l * G3;
                P.h_in_hi  = rd0 ? hhi0 : hhi1;
                P.h_in_lo  = rd0 ? hlo0 : hlo1;
                P.h_out_hi = rd0 ? hhi1 : hhi0;
                P.h_out_lo = rd0 ? hlo1 : hlo0;
                P.y_t      = ys + (size_t)t * BH;
                P.h_final  = (t == T_STEPS - 1) ? (hfin + (size_t)l * BH) : nullptr;
                P.t        = t;
            }
            dim3 gridB(HDIM / 16, BATCH / 16, na);
            gru_step_multi<<<gridB, 256, 0, stream>>>(sa, lengths);
        }
    }
}

// Round 3
// 12143.662 us; speedup vs baseline: 3.4772x; 1.2964x over previous
//
#include <hip/hip_runtime.h>
#include <hip/hip_bf16.h>

#define T_STEPS 256
#define BATCH   128
#define IDIM    512
#define HDIM    1024
#define NLAYERS 4
#define G3      (3 * HDIM)
#define BH      (BATCH * HDIM)   // 131072 elements

typedef __bf16 bf16_t;
typedef __bf16 bf16x4 __attribute__((ext_vector_type(4)));
typedef __bf16 bf16x8 __attribute__((ext_vector_type(8)));
typedef float  f32x4  __attribute__((ext_vector_type(4)));

__device__ __forceinline__ float sigm_f(float x) { return 1.0f / (1.0f + __expf(-x)); }
__device__ __forceinline__ float tanh_f(float x) { return 1.0f - 2.0f / (__expf(2.0f * x) + 1.0f); }

__device__ __forceinline__ bf16x8 cvt8(const float* p) {
    f32x4 v0 = *(const f32x4*)p;
    f32x4 v1 = *(const f32x4*)(p + 4);
    bf16x8 o;
    o[0] = (bf16_t)v0[0]; o[1] = (bf16_t)v0[1]; o[2] = (bf16_t)v0[2]; o[3] = (bf16_t)v0[3];
    o[4] = (bf16_t)v1[0]; o[5] = (bf16_t)v1[1]; o[6] = (bf16_t)v1[2]; o[7] = (bf16_t)v1[3];
    return o;
}

// fp32 -> bf16, 4 elements per thread. n4 = n/4.
__global__ void cvt_f2b(const float* __restrict__ s, bf16_t* __restrict__ d, int n4) {
    int i = blockIdx.x * blockDim.x + threadIdx.x;
    if (i < n4) {
        f32x4 v = ((const f32x4*)s)[i];
        bf16x4 o;
        o[0] = (bf16_t)v[0]; o[1] = (bf16_t)v[1];
        o[2] = (bf16_t)v[2]; o[3] = (bf16_t)v[3];
        ((bf16x4*)d)[i] = o;
    }
}

// fp32 h -> bf16 hi/lo split, 4 per thread over BH elements.
__global__ void split_h(const float* __restrict__ s,
                        bf16_t* __restrict__ hi, bf16_t* __restrict__ lo) {
    int i = blockIdx.x * blockDim.x + threadIdx.x;  // < BH/4
    f32x4 v = ((const f32x4*)s)[i];
    bf16x4 h, l;
#pragma unroll
    for (int j = 0; j < 4; ++j) {
        bf16_t t = (bf16_t)v[j];
        h[j] = t;
        l[j] = (bf16_t)(v[j] - (float)t);
    }
    ((bf16x4*)hi)[i] = h;
    ((bf16x4*)lo)[i] = l;
}

// Phase A: gi[chunk] = ys_rows @ W_ih^T + b_ih.  fp32 in (converted in-register),
// bf16 weights, fp32 out. One wave per WG; wave computes a 32x64 C-tile.
template <int HIN>
__global__ __launch_bounds__(64)
void gi_gemm(const float*  __restrict__ ysrc,
             const bf16_t* __restrict__ w_ih,
             const float*  __restrict__ b_ih,
             float* __restrict__ gi,
             int row0)
{
    const int lane = threadIdx.x;
    const int cq   = lane & 15;
    const int quad = lane >> 4;
    const int n0   = blockIdx.x * 64;
    const int m0   = blockIdx.y * 32;

    const float* a0p = ysrc + (size_t)(row0 + m0 + cq) * HIN + quad * 8;
    const float* a1p = a0p + (size_t)16 * HIN;
    const bf16_t* b0p = w_ih + (size_t)(n0 + cq) * HIN + quad * 8;
    const bf16_t* b1p = b0p + (size_t)16 * HIN;
    const bf16_t* b2p = b0p + (size_t)32 * HIN;
    const bf16_t* b3p = b0p + (size_t)48 * HIN;

    f32x4 a00{0,0,0,0}, a01 = a00, a02 = a00, a03 = a00;
    f32x4 a10 = a00, a11 = a00, a12 = a00, a13 = a00;

#pragma unroll 4
    for (int k = 0; k < HIN; k += 32) {
        bf16x8 fa0 = cvt8(a0p + k);
        bf16x8 fa1 = cvt8(a1p + k);
        bf16x8 fb0 = *(const bf16x8*)(b0p + k);
        bf16x8 fb1 = *(const bf16x8*)(b1p + k);
        bf16x8 fb2 = *(const bf16x8*)(b2p + k);
        bf16x8 fb3 = *(const bf16x8*)(b3p + k);
        a00 = __builtin_amdgcn_mfma_f32_16x16x32_bf16(fa0, fb0, a00, 0, 0, 0);
        a01 = __builtin_amdgcn_mfma_f32_16x16x32_bf16(fa0, fb1, a01, 0, 0, 0);
        a02 = __builtin_amdgcn_mfma_f32_16x16x32_bf16(fa0, fb2, a02, 0, 0, 0);
        a03 = __builtin_amdgcn_mfma_f32_16x16x32_bf16(fa0, fb3, a03, 0, 0, 0);
        a10 = __builtin_amdgcn_mfma_f32_16x16x32_bf16(fa1, fb0, a10, 0, 0, 0);
        a11 = __builtin_amdgcn_mfma_f32_16x16x32_bf16(fa1, fb1, a11, 0, 0, 0);
        a12 = __builtin_amdgcn_mfma_f32_16x16x32_bf16(fa1, fb2, a12, 0, 0, 0);
        a13 = __builtin_amdgcn_mfma_f32_16x16x32_bf16(fa1, fb3, a13, 0, 0, 0);
    }

    const float bb0 = b_ih[n0 + 0  + cq];
    const float bb1 = b_ih[n0 + 16 + cq];
    const float bb2 = b_ih[n0 + 32 + cq];
    const float bb3 = b_ih[n0 + 48 + cq];

#pragma unroll
    for (int i = 0; i < 4; ++i) {
        const int r0 = m0 + quad * 4 + i;
        const int r1 = r0 + 16;
        float* g0 = gi + (size_t)r0 * G3 + n0 + cq;
        float* g1 = gi + (size_t)r1 * G3 + n0 + cq;
        g0[0]  = a00[i] + bb0;  g0[16] = a01[i] + bb1;
        g0[32] = a02[i] + bb2;  g0[48] = a03[i] + bb3;
        g1[0]  = a10[i] + bb0;  g1[16] = a11[i] + bb1;
        g1[32] = a12[i] + bb2;  g1[48] = a13[i] + bb3;
    }
}

// Per-active-layer parameters for one fused timestep.
struct LayerStep {
    const float*  gi_t;      // (B, 3H) fp32, this timestep (includes b_ih)
    const bf16_t* w_hh;      // (3H, H) bf16
    const float*  b_hh;      // (3H) fp32
    const bf16_t* h_in_hi;
    const bf16_t* h_in_lo;
    bf16_t*       h_out_hi;
    bf16_t*       h_out_lo;
    float*        y_t;       // (B, H) fp32 output slice
    float*        h_final;   // (B, H) fp32 or nullptr
    int           t;
};
struct StepArgs { LayerStep L[NLAYERS]; };

// Phase B v2: one GRU timestep for up to 4 independent (layer, chunk) pairs.
// Grid (32 col-groups of 32, 2 batch-groups of 64, n_active) x 512 threads
// (8 waves = 4 K-quarters x 2 row-halves). Each wave computes 2 row-frags x
// 2 col-frags x 3 gates (12 f32x4 accs) -> every B-frag feeds 4 MFMAs and
// every A-frag 6 (weight L2 traffic 4x lower than v1). 96 KB LDS reduction,
// then all 8 waves each do gate math on one 16x16 subtile (same per-lane
// code as the verified v1 epilogue). Summation order identical to v1.
__global__ __launch_bounds__(512)
void gru_step_multi(StepArgs args, const int* __restrict__ lengths)
{
    __shared__ f32x4 red[4][3][2][2][2][64];  // [kq][gate][rh][rf][cf][lane] 96KB

    const LayerStep& A = args.L[blockIdx.z];

    const int tid  = threadIdx.x;
    const int wid  = tid >> 6;        // 0..7
    const int lane = tid & 63;
    const int cq   = lane & 15;
    const int quad = lane >> 4;
    const int c0   = blockIdx.x * 32; // hidden col group
    const int m0   = blockIdx.y * 64; // batch group

    // K-loop role: kq = K-quarter (256 wide), rh = row half (32 rows).
    const int kq = wid & 3;
    const int rh = wid >> 2;
    const int kofs = kq * 256 + quad * 8;

    const bf16_t* aph0 = A.h_in_hi + (size_t)(m0 + rh * 32 + cq) * HDIM + kofs;
    const bf16_t* aph1 = aph0 + (size_t)16 * HDIM;
    const bf16_t* apl0 = A.h_in_lo + (size_t)(m0 + rh * 32 + cq) * HDIM + kofs;
    const bf16_t* apl1 = apl0 + (size_t)16 * HDIM;
    const bf16_t* bp00 = A.w_hh + (size_t)(0 * HDIM + c0 + cq) * HDIM + kofs;
    const bf16_t* bp01 = bp00 + (size_t)16 * HDIM;
    const bf16_t* bp10 = A.w_hh + (size_t)(1 * HDIM + c0 + cq) * HDIM + kofs;
    const bf16_t* bp11 = bp10 + (size_t)16 * HDIM;
    const bf16_t* bp20 = A.w_hh + (size_t)(2 * HDIM + c0 + cq) * HDIM + kofs;
    const bf16_t* bp21 = bp20 + (size_t)16 * HDIM;

    f32x4 acc[2][2][3];   // [rf][cf][gate]
#pragma unroll
    for (int rf = 0; rf < 2; ++rf)
#pragma unroll
        for (int cf = 0; cf < 2; ++cf)
#pragma unroll
            for (int g = 0; g < 3; ++g) acc[rf][cf][g] = f32x4{0, 0, 0, 0};

#pragma unroll
    for (int k = 0; k < 256; k += 32) {
        bf16x8 Ah[2], Al[2], Bv[3][2];
        Ah[0] = *(const bf16x8*)(aph0 + k);
        Ah[1] = *(const bf16x8*)(aph1 + k);
        Al[0] = *(const bf16x8*)(apl0 + k);
        Al[1] = *(const bf16x8*)(apl1 + k);
        Bv[0][0] = *(const bf16x8*)(bp00 + k);
        Bv[0][1] = *(const bf16x8*)(bp01 + k);
        Bv[1][0] = *(const bf16x8*)(bp10 + k);
        Bv[1][1] = *(const bf16x8*)(bp11 + k);
        Bv[2][0] = *(const bf16x8*)(bp20 + k);
        Bv[2][1] = *(const bf16x8*)(bp21 + k);
        // hi first, then lo (per-acc order identical to v1)
#pragma unroll
        for (int rf = 0; rf < 2; ++rf)
#pragma unroll
            for (int cf = 0; cf < 2; ++cf)
#pragma unroll
                for (int g = 0; g < 3; ++g)
                    acc[rf][cf][g] = __builtin_amdgcn_mfma_f32_16x16x32_bf16(
                        Ah[rf], Bv[g][cf], acc[rf][cf][g], 0, 0, 0);
#pragma unroll
        for (int rf = 0; rf < 2; ++rf)
#pragma unroll
            for (int cf = 0; cf < 2; ++cf)
#pragma unroll
                for (int g = 0; g < 3; ++g)
                    acc[rf][cf][g] = __builtin_amdgcn_mfma_f32_16x16x32_bf16(
                        Al[rf], Bv[g][cf], acc[rf][cf][g], 0, 0, 0);
    }

#pragma unroll
    for (int rf = 0; rf < 2; ++rf)
#pragma unroll
        for (int cf = 0; cf < 2; ++cf)
#pragma unroll
            for (int g = 0; g < 3; ++g)
                red[kq][g][rh][rf][cf][lane] = acc[rf][cf][g];
    __syncthreads();

    // Gate phase: wave wid handles subtile (grh, grf, gcf); per-lane work is
    // identical to v1's epilogue (4 rows x 1 col).
    {
        const int grh = wid & 1;
        const int grf = (wid >> 1) & 1;
        const int gcf = wid >> 2;   // 0..1
        const int col = c0 + gcf * 16 + cq;

        f32x4 sr = ((red[0][0][grh][grf][gcf][lane] + red[1][0][grh][grf][gcf][lane])
                  +  red[2][0][grh][grf][gcf][lane]) + red[3][0][grh][grf][gcf][lane];
        f32x4 sz = ((red[0][1][grh][grf][gcf][lane] + red[1][1][grh][grf][gcf][lane])
                  +  red[2][1][grh][grf][gcf][lane]) + red[3][1][grh][grf][gcf][lane];
        f32x4 sn = ((red[0][2][grh][grf][gcf][lane] + red[1][2][grh][grf][gcf][lane])
                  +  red[2][2][grh][grf][gcf][lane]) + red[3][2][grh][grf][gcf][lane];

        const float bhr = A.b_hh[col];
        const float bhz = A.b_hh[HDIM + col];
        const float bhn = A.b_hh[2 * HDIM + col];

#pragma unroll
        for (int i = 0; i < 4; ++i) {
            const int row = m0 + grh * 32 + grf * 16 + quad * 4 + i;  // batch idx
            const size_t oh = (size_t)row * HDIM + col;
            const float* gr = A.gi_t + (size_t)row * G3;
            const float ir  = gr[col];
            const float iz  = gr[HDIM + col];
            const float inn = gr[2 * HDIM + col];
            const float hold = (float)A.h_in_hi[oh] + (float)A.h_in_lo[oh];
            const float r = sigm_f(ir + sr[i] + bhr);
            const float z = sigm_f(iz + sz[i] + bhz);
            const float n = tanh_f(inn + r * (sn[i] + bhn));
            const float hnew = (1.0f - z) * n + z * hold;
            const bool msk = A.t < lengths[row];
            const float hnext = msk ? hnew : hold;
            const bf16_t hb = (bf16_t)hnext;
            A.h_out_hi[oh] = hb;
            A.h_out_lo[oh] = (bf16_t)(hnext - (float)hb);
            A.y_t[oh] = msk ? hnew : 0.0f;
            if (A.h_final) A.h_final[oh] = hnext;
        }
    }
}

extern "C" void kernel_launch(void* const* d_in, const int* in_sizes, int n_in,
                              void* d_out, int out_size, void* d_ws, size_t ws_size,
                              hipStream_t stream) {
    const float* x         = (const float*)d_in[0];
    const float* hidden    = (const float*)d_in[1];
    const float* w_ih0     = (const float*)d_in[2];
    const float* w_ih_rest = (const float*)d_in[3];
    const float* w_hh      = (const float*)d_in[4];
    const float* b_ih      = (const float*)d_in[5];
    const float* b_hh      = (const float*)d_in[6];
    const int*   lengths   = (const int*)d_in[8];

    float* ys   = (float*)d_out;               // (T, B, H) fp32
    float* hfin = ys + (size_t)T_STEPS * BH;   // (L, B, H) fp32

    // Workspace layout: bf16 weights (47.2 MB), per-layer h hi/lo ping-pong
    // (4 x 1 MB), per-layer gi chunk buffers (4 x chunk x 128 x 3072 x 4 B).
    char* ws = (char*)d_ws;
    bf16_t* wb_ih0  = (bf16_t*)ws;                                   // 3072*512
    bf16_t* wb_rest = wb_ih0 + (size_t)G3 * IDIM;                    // 3*3072*1024
    bf16_t* wb_hh   = wb_rest + (size_t)(NLAYERS - 1) * G3 * HDIM;   // 4*3072*1024
    bf16_t* hbase   = wb_hh + (size_t)NLAYERS * G3 * HDIM;           // 4 layers * 4*BH
    float*  gi_base = (float*)(hbase + (size_t)NLAYERS * 4 * BH);

    const size_t fixed_bytes = (size_t)((char*)gi_base - ws);
    // Runtime chunk size: largest of {16,8,4,2} whose gi buffers fit ws.
    int chunk = 16;
    while (chunk > 2 &&
           fixed_bytes + (size_t)NLAYERS * chunk * BATCH * G3 * sizeof(float) > ws_size)
        chunk >>= 1;
    const int nch = T_STEPS / chunk;
    const size_t gi_stride = (size_t)chunk * BATCH * G3;  // floats per layer buffer

    // Convert all weights fp32 -> bf16 once.
    {
        int n4;
        n4 = G3 * IDIM / 4;
        cvt_f2b<<<(n4 + 255) / 256, 256, 0, stream>>>(w_ih0, wb_ih0, n4);
        n4 = (NLAYERS - 1) * G3 * HDIM / 4;
        cvt_f2b<<<(n4 + 255) / 256, 256, 0, stream>>>(w_ih_rest, wb_rest, n4);
        n4 = NLAYERS * G3 * HDIM / 4;
        cvt_f2b<<<(n4 + 255) / 256, 256, 0, stream>>>(w_hh, wb_hh, n4);
    }

    // Seed every layer's h ping-pong slot 0 with its initial hidden state.
    for (int l = 0; l < NLAYERS; ++l) {
        bf16_t* hb = hbase + (size_t)l * 4 * BH;
        split_h<<<BH / 4 / 256, 256, 0, stream>>>(hidden + (size_t)l * BH, hb, hb + BH);
    }

    const dim3 gridA(G3 / 64, chunk * BATCH / 32);

    // Wavefront over chunks: iteration s runs (layer l, chunk c=s-l) for all
    // valid l concurrently. Layer l's Phase A at iteration s reads ys chunk c
    // (written by layer l-1 at iteration s-1) before layer l's own steps
    // overwrite that ys slice later in this iteration (stream order).
    for (int s = 0; s < nch + NLAYERS - 1; ++s) {
        // Phase A for each newly-active (layer, chunk).
        for (int l = 0; l < NLAYERS; ++l) {
            const int c = s - l;
            if (c < 0 || c >= nch) continue;
            float* gi_l = gi_base + (size_t)l * gi_stride;
            const bf16_t* wb_ih_l = (l == 0) ? wb_ih0 : (wb_rest + (size_t)(l - 1) * G3 * HDIM);
            const float*  b_ih_l  = b_ih + (size_t)l * G3;
            const int row0 = c * chunk * BATCH;
            if (l == 0) {
                gi_gemm<IDIM><<<gridA, 64, 0, stream>>>(x, wb_ih_l, b_ih_l, gi_l, row0);
            } else {
                gi_gemm<HDIM><<<gridA, 64, 0, stream>>>(ys, wb_ih_l, b_ih_l, gi_l, row0);
            }
        }
        // Fused steps: all active layers advance together.
        for (int tt = 0; tt < chunk; ++tt) {
            StepArgs sa;
            int na = 0;
            for (int l = 0; l < NLAYERS; ++l) {
                const int c = s - l;
                if (c < 0 || c >= nch) continue;
                const int t = c * chunk + tt;
                const bool rd0 = ((t & 1) == 0);
                bf16_t* hb = hbase + (size_t)l * 4 * BH;
                bf16_t* hhi0 = hb, *hlo0 = hb + BH, *hhi1 = hb + 2 * BH, *hlo1 = hb + 3 * BH;
                LayerStep& P = sa.L[na++];
                P.gi_t     = gi_base + (size_t)l * gi_stride + (size_t)tt * BATCH * G3;
                P.w_hh     = wb_hh + (size_t)l * G3 * HDIM;
                P.b_hh     = b_hh + (size_t)l * G3;
                P.h_in_hi  = rd0 ? hhi0 : hhi1;
                P.h_in_lo  = rd0 ? hlo0 : hlo1;
                P.h_out_hi = rd0 ? hhi1 : hhi0;
                P.h_out_lo = rd0 ? hlo1 : hlo0;
                P.y_t      = ys + (size_t)t * BH;
                P.h_final  = (t == T_STEPS - 1) ? (hfin + (size_t)l * BH) : nullptr;
                P.t        = t;
            }
            dim3 gridB(HDIM / 32, BATCH / 64, na);
            gru_step_multi<<<gridB, 512, 0, stream>>>(sa, lengths);
        }
    }
}

// Round 4
// 11142.104 us; speedup vs baseline: 3.7898x; 1.0899x over previous
//
#include <hip/hip_runtime.h>
#include <hip/hip_bf16.h>

#define T_STEPS 256
#define BATCH   128
#define IDIM    512
#define HDIM    1024
#define NLAYERS 4
#define G3      (3 * HDIM)
#define BH      (BATCH * HDIM)   // 131072 elements
#define CHUNK   16               // wavefront chunk (timesteps)
#define RING    (2 * CHUNK)      // inter-layer ring depth (slots)

typedef __bf16 bf16_t;
typedef __bf16 bf16x4 __attribute__((ext_vector_type(4)));
typedef __bf16 bf16x8 __attribute__((ext_vector_type(8)));
typedef float  f32x4  __attribute__((ext_vector_type(4)));

__device__ __forceinline__ float sigm_f(float x) { return 1.0f / (1.0f + __expf(-x)); }
__device__ __forceinline__ float tanh_f(float x) { return 1.0f - 2.0f / (__expf(2.0f * x) + 1.0f); }

// fp32 -> bf16, 4 elements per thread. n4 = n/4.
__global__ void cvt_f2b(const float* __restrict__ s, bf16_t* __restrict__ d, int n4) {
    int i = blockIdx.x * blockDim.x + threadIdx.x;
    if (i < n4) {
        f32x4 v = ((const f32x4*)s)[i];
        bf16x4 o;
        o[0] = (bf16_t)v[0]; o[1] = (bf16_t)v[1];
        o[2] = (bf16_t)v[2]; o[3] = (bf16_t)v[3];
        ((bf16x4*)d)[i] = o;
    }
}

// fp32 h -> bf16 hi/lo split, 4 per thread over BH elements.
__global__ void split_h(const float* __restrict__ s,
                        bf16_t* __restrict__ hi, bf16_t* __restrict__ lo) {
    int i = blockIdx.x * blockDim.x + threadIdx.x;  // < BH/4
    f32x4 v = ((const f32x4*)s)[i];
    bf16x4 h, l;
#pragma unroll
    for (int j = 0; j < 4; ++j) {
        bf16_t t = (bf16_t)v[j];
        h[j] = t;
        l[j] = (bf16_t)(v[j] - (float)t);
    }
    ((bf16x4*)hi)[i] = h;
    ((bf16x4*)lo)[i] = l;
}

// Per-active-layer parameters for one fused timestep.
struct LayerStep {
    const bf16_t* inp;       // (B, kin) bf16 input slice for this t
    const bf16_t* w_ih;      // (3H, kin) bf16
    const bf16_t* w_hh;      // (3H, H) bf16
    const float*  b_ih;      // (3H) fp32
    const float*  b_hh;      // (3H) fp32
    const bf16_t* h_in_hi;
    const bf16_t* h_in_lo;
    bf16_t*       h_out_hi;
    bf16_t*       h_out_lo;
    bf16_t*       y_bf;      // (B, H) bf16 ring slot, or nullptr (last layer)
    float*        y_f32;     // (B, H) fp32 ys slice, or nullptr (layers 0..2)
    float*        h_final;   // (B, H) fp32 or nullptr
    int           t;
    int           kin;       // 512 (layer 0) or 1024
};
struct StepArgs { LayerStep L[NLAYERS]; };

// Phase B v3: one full GRU timestep (input projection + hidden projection +
// gates) for up to 4 independent (layer, chunk) pairs. Grid (32 col-groups
// of 32, 2 batch-groups of 64, n_active) x 512 threads (8 waves = 4
// K-quarters x 2 row-halves). Each wave: hidden GEMM (K=1024, hi+lo) and
// input GEMM (K=kin, single bf16 pass) over its K-quarter. r/z gates share
// accumulators between input and hidden (summed in epilogue anyway); the n
// gate keeps input (inn) and hidden (hn) separate. 128 KB LDS reduction,
// then all 8 waves do gate math on one 16x16 subtile each.
__global__ __launch_bounds__(512)
void gru_step_multi(StepArgs args, const int* __restrict__ lengths)
{
    __shared__ f32x4 red[4][4][2][2][2][64];  // [kq][kind][rh][rf][cf][lane] 128KB
                                              // kind: 0=r, 1=z, 2=hn, 3=in

    const LayerStep& A = args.L[blockIdx.z];

    const int tid  = threadIdx.x;
    const int wid  = tid >> 6;        // 0..7
    const int lane = tid & 63;
    const int cq   = lane & 15;
    const int quad = lane >> 4;
    const int c0   = blockIdx.x * 32; // hidden col group
    const int m0   = blockIdx.y * 64; // batch group

    // K-loop role: kq = K-quarter, rh = row half (32 rows).
    const int kq = wid & 3;
    const int rh = wid >> 2;

    f32x4 arz[2][2][2];   // [rf][cf][gate r/z]  (input + hidden combined)
    f32x4 ahn[2][2];      // [rf][cf] hidden n
    f32x4 ain[2][2];      // [rf][cf] input n
#pragma unroll
    for (int rf = 0; rf < 2; ++rf)
#pragma unroll
        for (int cf = 0; cf < 2; ++cf) {
            arz[rf][cf][0] = f32x4{0, 0, 0, 0};
            arz[rf][cf][1] = f32x4{0, 0, 0, 0};
            ahn[rf][cf]    = f32x4{0, 0, 0, 0};
            ain[rf][cf]    = f32x4{0, 0, 0, 0};
        }

    // ---- Hidden projection: K = 1024 (quarter 256), hi then lo ----
    {
        const int kofs = kq * 256 + quad * 8;
        const bf16_t* aph0 = A.h_in_hi + (size_t)(m0 + rh * 32 + cq) * HDIM + kofs;
        const bf16_t* aph1 = aph0 + (size_t)16 * HDIM;
        const bf16_t* apl0 = A.h_in_lo + (size_t)(m0 + rh * 32 + cq) * HDIM + kofs;
        const bf16_t* apl1 = apl0 + (size_t)16 * HDIM;
        const bf16_t* bp00 = A.w_hh + (size_t)(0 * HDIM + c0 + cq) * HDIM + kofs;
        const bf16_t* bp01 = bp00 + (size_t)16 * HDIM;
        const bf16_t* bp10 = A.w_hh + (size_t)(1 * HDIM + c0 + cq) * HDIM + kofs;
        const bf16_t* bp11 = bp10 + (size_t)16 * HDIM;
        const bf16_t* bp20 = A.w_hh + (size_t)(2 * HDIM + c0 + cq) * HDIM + kofs;
        const bf16_t* bp21 = bp20 + (size_t)16 * HDIM;

#pragma unroll
        for (int k = 0; k < 256; k += 32) {
            bf16x8 Ah[2], Al[2], Bv[3][2];
            Ah[0] = *(const bf16x8*)(aph0 + k);
            Ah[1] = *(const bf16x8*)(aph1 + k);
            Al[0] = *(const bf16x8*)(apl0 + k);
            Al[1] = *(const bf16x8*)(apl1 + k);
            Bv[0][0] = *(const bf16x8*)(bp00 + k);
            Bv[0][1] = *(const bf16x8*)(bp01 + k);
            Bv[1][0] = *(const bf16x8*)(bp10 + k);
            Bv[1][1] = *(const bf16x8*)(bp11 + k);
            Bv[2][0] = *(const bf16x8*)(bp20 + k);
            Bv[2][1] = *(const bf16x8*)(bp21 + k);
            // hi first, then lo (per-acc order identical to v2)
#pragma unroll
            for (int rf = 0; rf < 2; ++rf)
#pragma unroll
                for (int cf = 0; cf < 2; ++cf) {
                    arz[rf][cf][0] = __builtin_amdgcn_mfma_f32_16x16x32_bf16(
                        Ah[rf], Bv[0][cf], arz[rf][cf][0], 0, 0, 0);
                    arz[rf][cf][1] = __builtin_amdgcn_mfma_f32_16x16x32_bf16(
                        Ah[rf], Bv[1][cf], arz[rf][cf][1], 0, 0, 0);
                    ahn[rf][cf] = __builtin_amdgcn_mfma_f32_16x16x32_bf16(
                        Ah[rf], Bv[2][cf], ahn[rf][cf], 0, 0, 0);
                }
#pragma unroll
            for (int rf = 0; rf < 2; ++rf)
#pragma unroll
                for (int cf = 0; cf < 2; ++cf) {
                    arz[rf][cf][0] = __builtin_amdgcn_mfma_f32_16x16x32_bf16(
                        Al[rf], Bv[0][cf], arz[rf][cf][0], 0, 0, 0);
                    arz[rf][cf][1] = __builtin_amdgcn_mfma_f32_16x16x32_bf16(
                        Al[rf], Bv[1][cf], arz[rf][cf][1], 0, 0, 0);
                    ahn[rf][cf] = __builtin_amdgcn_mfma_f32_16x16x32_bf16(
                        Al[rf], Bv[2][cf], ahn[rf][cf], 0, 0, 0);
                }
        }
    }

    // ---- Input projection: K = kin (quarter kin/4), single bf16 pass ----
    {
        const int kin  = A.kin;
        const int qw   = kin >> 2;            // 256 or 128
        const int kofs = kq * qw + quad * 8;
        const bf16_t* axp0 = A.inp + (size_t)(m0 + rh * 32 + cq) * kin + kofs;
        const bf16_t* axp1 = axp0 + (size_t)16 * kin;
        const bf16_t* wp00 = A.w_ih + (size_t)(0 * HDIM + c0 + cq) * kin + kofs;
        const bf16_t* wp01 = wp00 + (size_t)16 * kin;
        const bf16_t* wp10 = A.w_ih + (size_t)(1 * HDIM + c0 + cq) * kin + kofs;
        const bf16_t* wp11 = wp10 + (size_t)16 * kin;
        const bf16_t* wp20 = A.w_ih + (size_t)(2 * HDIM + c0 + cq) * kin + kofs;
        const bf16_t* wp21 = wp20 + (size_t)16 * kin;

#pragma unroll 4
        for (int k = 0; k < qw; k += 32) {
            bf16x8 Ax[2], Wv[3][2];
            Ax[0] = *(const bf16x8*)(axp0 + k);
            Ax[1] = *(const bf16x8*)(axp1 + k);
            Wv[0][0] = *(const bf16x8*)(wp00 + k);
            Wv[0][1] = *(const bf16x8*)(wp01 + k);
            Wv[1][0] = *(const bf16x8*)(wp10 + k);
            Wv[1][1] = *(const bf16x8*)(wp11 + k);
            Wv[2][0] = *(const bf16x8*)(wp20 + k);
            Wv[2][1] = *(const bf16x8*)(wp21 + k);
#pragma unroll
            for (int rf = 0; rf < 2; ++rf)
#pragma unroll
                for (int cf = 0; cf < 2; ++cf) {
                    arz[rf][cf][0] = __builtin_amdgcn_mfma_f32_16x16x32_bf16(
                        Ax[rf], Wv[0][cf], arz[rf][cf][0], 0, 0, 0);
                    arz[rf][cf][1] = __builtin_amdgcn_mfma_f32_16x16x32_bf16(
                        Ax[rf], Wv[1][cf], arz[rf][cf][1], 0, 0, 0);
                    ain[rf][cf] = __builtin_amdgcn_mfma_f32_16x16x32_bf16(
                        Ax[rf], Wv[2][cf], ain[rf][cf], 0, 0, 0);
                }
        }
    }

#pragma unroll
    for (int rf = 0; rf < 2; ++rf)
#pragma unroll
        for (int cf = 0; cf < 2; ++cf) {
            red[kq][0][rh][rf][cf][lane] = arz[rf][cf][0];
            red[kq][1][rh][rf][cf][lane] = arz[rf][cf][1];
            red[kq][2][rh][rf][cf][lane] = ahn[rf][cf];
            red[kq][3][rh][rf][cf][lane] = ain[rf][cf];
        }
    __syncthreads();

    // Gate phase: wave wid handles subtile (grh, grf, gcf).
    {
        const int grh = wid & 1;
        const int grf = (wid >> 1) & 1;
        const int gcf = wid >> 2;   // 0..1
        const int col = c0 + gcf * 16 + cq;

        f32x4 sr = ((red[0][0][grh][grf][gcf][lane] + red[1][0][grh][grf][gcf][lane])
                  +  red[2][0][grh][grf][gcf][lane]) + red[3][0][grh][grf][gcf][lane];
        f32x4 sz = ((red[0][1][grh][grf][gcf][lane] + red[1][1][grh][grf][gcf][lane])
                  +  red[2][1][grh][grf][gcf][lane]) + red[3][1][grh][grf][gcf][lane];
        f32x4 shn = ((red[0][2][grh][grf][gcf][lane] + red[1][2][grh][grf][gcf][lane])
                   +  red[2][2][grh][grf][gcf][lane]) + red[3][2][grh][grf][gcf][lane];
        f32x4 sin_ = ((red[0][3][grh][grf][gcf][lane] + red[1][3][grh][grf][gcf][lane])
                    +  red[2][3][grh][grf][gcf][lane]) + red[3][3][grh][grf][gcf][lane];

        const float bir = A.b_ih[col];
        const float biz = A.b_ih[HDIM + col];
        const float bin = A.b_ih[2 * HDIM + col];
        const float bhr = A.b_hh[col];
        const float bhz = A.b_hh[HDIM + col];
        const float bhn = A.b_hh[2 * HDIM + col];

#pragma unroll
        for (int i = 0; i < 4; ++i) {
            const int row = m0 + grh * 32 + grf * 16 + quad * 4 + i;  // batch idx
            const size_t oh = (size_t)row * HDIM + col;
            const float hold = (float)A.h_in_hi[oh] + (float)A.h_in_lo[oh];
            const float r = sigm_f(sr[i] + bir + bhr);
            const float z = sigm_f(sz[i] + biz + bhz);
            const float n = tanh_f((sin_[i] + bin) + r * (shn[i] + bhn));
            const float hnew = (1.0f - z) * n + z * hold;
            const bool msk = A.t < lengths[row];
            const float hnext = msk ? hnew : hold;
            const bf16_t hb = (bf16_t)hnext;
            A.h_out_hi[oh] = hb;
            A.h_out_lo[oh] = (bf16_t)(hnext - (float)hb);
            const float yv = msk ? hnew : 0.0f;
            if (A.y_bf)  A.y_bf[oh]  = (bf16_t)yv;
            if (A.y_f32) A.y_f32[oh] = yv;
            if (A.h_final) A.h_final[oh] = hnext;
        }
    }
}

extern "C" void kernel_launch(void* const* d_in, const int* in_sizes, int n_in,
                              void* d_out, int out_size, void* d_ws, size_t ws_size,
                              hipStream_t stream) {
    const float* x         = (const float*)d_in[0];
    const float* hidden    = (const float*)d_in[1];
    const float* w_ih0     = (const float*)d_in[2];
    const float* w_ih_rest = (const float*)d_in[3];
    const float* w_hh      = (const float*)d_in[4];
    const float* b_ih      = (const float*)d_in[5];
    const float* b_hh      = (const float*)d_in[6];
    const int*   lengths   = (const int*)d_in[8];

    float* ys   = (float*)d_out;               // (T, B, H) fp32 — last layer only
    float* hfin = ys + (size_t)T_STEPS * BH;   // (L, B, H) fp32

    // Workspace (~108 MB): bf16 weights (47.2), per-layer h hi/lo ping-pong
    // (4 MB), x in bf16 (32 MB), inter-layer bf16 rings (3 x 8 MB).
    char* ws = (char*)d_ws;
    bf16_t* wb_ih0  = (bf16_t*)ws;                                   // 3072*512
    bf16_t* wb_rest = wb_ih0 + (size_t)G3 * IDIM;                    // 3*3072*1024
    bf16_t* wb_hh   = wb_rest + (size_t)(NLAYERS - 1) * G3 * HDIM;   // 4*3072*1024
    bf16_t* hbase   = wb_hh + (size_t)NLAYERS * G3 * HDIM;           // 4 layers * 4*BH
    bf16_t* xb      = hbase + (size_t)NLAYERS * 4 * BH;              // T*B*IDIM
    bf16_t* ybuf    = xb + (size_t)T_STEPS * BATCH * IDIM;           // 3 * RING * BH

    // Convert all weights + x fp32 -> bf16 once.
    {
        int n4;
        n4 = G3 * IDIM / 4;
        cvt_f2b<<<(n4 + 255) / 256, 256, 0, stream>>>(w_ih0, wb_ih0, n4);
        n4 = (NLAYERS - 1) * G3 * HDIM / 4;
        cvt_f2b<<<(n4 + 255) / 256, 256, 0, stream>>>(w_ih_rest, wb_rest, n4);
        n4 = NLAYERS * G3 * HDIM / 4;
        cvt_f2b<<<(n4 + 255) / 256, 256, 0, stream>>>(w_hh, wb_hh, n4);
        n4 = T_STEPS * BATCH * IDIM / 4;
        cvt_f2b<<<(n4 + 255) / 256, 256, 0, stream>>>(x, xb, n4);
    }

    // Seed every layer's h ping-pong slot 0 with its initial hidden state.
    for (int l = 0; l < NLAYERS; ++l) {
        bf16_t* hb = hbase + (size_t)l * 4 * BH;
        split_h<<<BH / 4 / 256, 256, 0, stream>>>(hidden + (size_t)l * BH, hb, hb + BH);
    }

    const int nch = T_STEPS / CHUNK;

    // Wavefront over chunks: iteration s advances (layer l, chunk c=s-l) for
    // all valid l in one fused launch per timestep. Layer l at time t reads
    // layer l-1's output from ring slot (t & RING-1), written in iteration
    // s-1; within an iteration, layer l-1 writes slots (t+CHUNK) & RING-1 —
    // disjoint, so no intra-launch race.
    for (int s = 0; s < nch + NLAYERS - 1; ++s) {
        for (int tt = 0; tt < CHUNK; ++tt) {
            StepArgs sa;
            int na = 0;
            for (int l = 0; l < NLAYERS; ++l) {
                const int c = s - l;
                if (c < 0 || c >= nch) continue;
                const int t = c * CHUNK + tt;
                const bool rd0 = ((t & 1) == 0);
                bf16_t* hb = hbase + (size_t)l * 4 * BH;
                bf16_t* hhi0 = hb, *hlo0 = hb + BH, *hhi1 = hb + 2 * BH, *hlo1 = hb + 3 * BH;
                LayerStep& P = sa.L[na++];
                if (l == 0) {
                    P.inp = xb + (size_t)t * BATCH * IDIM;
                    P.kin = IDIM;
                    P.w_ih = wb_ih0;
                } else {
                    P.inp = ybuf + (size_t)(l - 1) * RING * BH
                                 + (size_t)(t & (RING - 1)) * BH;
                    P.kin = HDIM;
                    P.w_ih = wb_rest + (size_t)(l - 1) * G3 * HDIM;
                }
                P.w_hh     = wb_hh + (size_t)l * G3 * HDIM;
                P.b_ih     = b_ih + (size_t)l * G3;
                P.b_hh     = b_hh + (size_t)l * G3;
                P.h_in_hi  = rd0 ? hhi0 : hhi1;
                P.h_in_lo  = rd0 ? hlo0 : hlo1;
                P.h_out_hi = rd0 ? hhi1 : hhi0;
                P.h_out_lo = rd0 ? hlo1 : hlo0;
                P.y_bf     = (l < NLAYERS - 1)
                           ? (ybuf + (size_t)l * RING * BH + (size_t)(t & (RING - 1)) * BH)
                           : nullptr;
                P.y_f32    = (l == NLAYERS - 1) ? (ys + (size_t)t * BH) : nullptr;
                P.h_final  = (t == T_STEPS - 1) ? (hfin + (size_t)l * BH) : nullptr;
                P.t        = t;
            }
            dim3 gridB(HDIM / 32, BATCH / 64, na);
            gru_step_multi<<<gridB, 512, 0, stream>>>(sa, lengths);
        }
    }
}